// Round 9
// baseline (706.318 us; speedup 1.0000x reference)
//
#include <hip/hip_runtime.h>
#include <hip/hip_bf16.h>

#define NV 40000
#define FD 256
#define HD 128
#define ED 640000
#define NG 3
#define NH (NV*HD)

#define CH  64            // edge chunks per graph
#define EPC (ED/CH)       // 10000 edges per chunk
#define NB  625           // buckets of 64 nodes

typedef unsigned short u16;
typedef unsigned int   u32;
typedef __attribute__((ext_vector_type(8))) u16    u16x8;
typedef __attribute__((ext_vector_type(8))) __bf16 bf16x8;
typedef __attribute__((ext_vector_type(4))) float  f32x4;
typedef __attribute__((ext_vector_type(2))) u32    u32x2;

__device__ inline u16 f2b(float f){ __bf16 h = (__bf16)f; return __builtin_bit_cast(u16, h); }
__device__ inline float b2f(u16 u){ u32 x = ((u32)u)<<16; return __builtin_bit_cast(float, x); }
__device__ inline void acc2(u32 w, float&a, float&b){
  a += __builtin_bit_cast(float, w<<16);
  b += __builtin_bit_cast(float, w & 0xFFFF0000u);
}

// ---------------- combo: bucket hist (192 blocks) + weight prep (833 blocks) ----
__device__ inline void tr_seg(const float* __restrict__ src, u16* __restrict__ dst,
                              int K, int NN, long idx, long total){
  if (idx>=total) return;
  long per=(long)K*NN; long mat=idx/per; long rem=idx-mat*per;
  int k=(int)(rem/NN), c=(int)(rem-(long)k*NN);
  dst[mat*per+(long)c*K+k]=f2b(src[idx]);
}

__global__ __launch_bounds__(256) void htr_k(
    const int* __restrict__ ei, int* __restrict__ btot,
    const float* fc1W, const float* fc2W,
    const float* c1W, const float* c2W, const float* c1b,
    const float* d1W, const float* d2W, const float* d1b,
    u16* w_fc1, u16* w_fc2, u16* w_ce, u16* w_cd,
    float* t_enc, float* t_dec)
{
  __shared__ int h[NB];
  int b = blockIdx.x, t = threadIdx.x;
  if (b < 192){
    int ch = b % CH, g = b / CH;
    for (int i=t;i<NB;i+=256) h[i]=0;
    __syncthreads();
    const int* cc = ei + (long)g*2*ED + ED + ch*EPC;
    for (int j=t;j<EPC;j+=256) atomicAdd(&h[cc[j]>>6],1);
    __syncthreads();
    for (int bb=t;bb<NB;bb+=256){ int v=h[bb]; if(v) atomicAdd(&btot[g*NB+bb], v); }
    return;
  }
  int blk = b - 192;
  if (blk < 384){
    tr_seg(fc1W, w_fc1, FD, HD, (long)blk*256+t, (long)NG*FD*HD);
  } else if (blk < 512){
    tr_seg(fc2W, w_fc2, HD, FD, (long)(blk-384)*256+t, (long)HD*FD);
  } else if (blk < 832){
    int bb=blk-512;
    int mat=bb>>6;
    int local=(bb&63)*256+t;
    int n=local>>7, k=local&127;
    const float* W1; const float* W2; u16* dst;
    if (mat<3){ W1=c1W+(long)mat*HD*HD; W2=c2W+(long)mat*HD*HD; dst=w_ce+(long)mat*HD*HD; }
    else { int md=mat-3; W1=d1W+(long)md*HD*HD; W2=d2W+(long)md*HD*HD; dst=w_cd+(long)md*HD*HD; }
    float s=0.f;
    for (int j=0;j<HD;j++) s += W1[k*HD+j]*W2[j*HD+n];
    dst[(long)n*HD+k]=f2b(s);
  } else {
    for (int idx=t; idx<768; idx+=256){
      int which=idx>>7, n=idx&127;
      const float* bv; const float* W; float* dst;
      if (which<3){ bv=c1b+which*HD; W=c2W+(long)which*HD*HD; dst=t_enc+which*HD; }
      else { int w2=which-3; bv=d1b+w2*HD; W=d2W+(long)w2*HD*HD; dst=t_dec+w2*HD; }
      float s=0.f;
      for (int k=0;k<HD;k++) s += bv[k]*W[(long)k*HD+n];
      dst[n]=s;
    }
  }
}

__global__ void scanB_k(const int* __restrict__ btot, int* __restrict__ base, int* __restrict__ gcur){
  __shared__ int wsum[16];
  int tid=threadIdx.x, lane=tid&63, wv=tid>>6;
  for (int g=0; g<NG; ++g){
    int v = (tid<NB)? btot[g*NB+tid] : 0;
    int s=v;
    #pragma unroll
    for (int d=1; d<64; d<<=1){ int u=__shfl_up(s,d,64); if(lane>=d) s+=u; }
    if (lane==63) wsum[wv]=s;
    __syncthreads();
    if (wv==0){
      int t3=(lane<16)?wsum[lane]:0;
      #pragma unroll
      for (int d=1; d<16; d<<=1){ int u=__shfl_up(t3,d,64); if(lane>=d) t3+=u; }
      if (lane<16) wsum[lane]=t3;
    }
    __syncthreads();
    int incl = s + (wv>0? wsum[wv-1]:0);
    if (tid<NB){
      base[g*(NB+1)+tid]=incl-v;
      gcur[g*NB+tid]=incl-v;
      if (tid==NB-1) base[g*(NB+1)+NB]=incl;
    }
    __syncthreads();
  }
}

__global__ __launch_bounds__(256) void scat_k(const int* __restrict__ ei, int* __restrict__ gcur,
                                              u32* __restrict__ temp){
  int ch=blockIdx.x, g=blockIdx.y, t=threadIdx.x;
  __shared__ int h[NB];
  __shared__ int cur[NB];
  for (int i=t;i<NB;i+=256) h[i]=0;
  __syncthreads();
  const int* rr = ei + (long)g*2*ED + ch*EPC;
  const int* cc = rr + ED;
  for (int j=t;j<EPC;j+=256) atomicAdd(&h[cc[j]>>6],1);
  __syncthreads();
  for (int b=t;b<NB;b+=256){ int v=h[b]; cur[b] = v? atomicAdd(&gcur[g*NB+b], v) : 0; }
  __syncthreads();
  u32* tg = temp + (long)g*ED;
  for (int j=t;j<EPC;j+=256){
    int r=rr[j], c=cc[j];
    int pos=atomicAdd(&cur[c>>6],1);
    tg[pos]=((u32)(c&63)<<16)|(u32)r;
  }
}

// bucket-local counting sort -> u16 CSR + cptr + dinv
__global__ __launch_bounds__(256) void sort_k(const u32* __restrict__ temp, const int* __restrict__ base,
                                              u16* __restrict__ csr, int* __restrict__ cptr,
                                              float* __restrict__ dinv){
  int b=blockIdx.x, g=blockIdx.y, t=threadIdx.x;
  __shared__ int cnt[64];
  __shared__ int cur[64];
  if (t<64) cnt[t]=0;
  __syncthreads();
  const u32* tg = temp + (long)g*ED;
  int s=base[g*(NB+1)+b], e=base[g*(NB+1)+b+1];
  for (int i=s+t;i<e;i+=256) atomicAdd(&cnt[tg[i]>>16],1);
  __syncthreads();
  if (t<64){
    int v=cnt[t];
    int sc=v;
    #pragma unroll
    for (int d=1;d<64;d<<=1){ int u=__shfl_up(sc,d,64); if(t>=d) sc+=u; }
    int st = s + sc - v;
    cur[t]=st;
    cptr[(long)g*(NV+1) + b*64 + t] = st;
    if (b==NB-1 && t==63) cptr[(long)g*(NV+1)+NV] = e;
    dinv[(long)g*NV + b*64 + t] = rsqrtf((float)v+1.0f);
  }
  __syncthreads();
  u16* cg = csr + (long)g*ED;
  for (int i=s+t;i<e;i+=256){
    u32 tt=tg[i];
    int pos=atomicAdd(&cur[tt>>16],1);
    cg[pos]=(u16)(tt&0xFFFF);
  }
}

// --------------- agg body: half-wave dwordx2 gather, UNIFORM trip counts --------
// All row gathers use NON-TEMPORAL loads: the gather table (10 MB/graph) has no
// L2-resident reuse (lines evicted before their ~16-fold reuse recurs), so `nt`
// (no-allocate/evict-first) removes ~330 MB/hop of useless L2 fill traffic.
// EXEC-mask safety unchanged from round 8 (uniform trip counts; clamped shfl src).
__device__ __forceinline__ void agg_body(
    const u16* __restrict__ xw, const u16* __restrict__ csr,
    const int* __restrict__ cptr, const float* __restrict__ dinv,
    u16* __restrict__ outB, int c, int lane, int scOut)
{
  const u32x2* xp2 = (const u32x2*)xw;   // row r: xp2[r*32 + hl] = features 4hl..4hl+3
  int hl = lane & 31;
  int hi = lane >> 5;
  float dc = dinv[c];
  float s0=0.f, s1=0.f, s2=0.f, s3=0.f;
  {
    u32x2 v = __builtin_nontemporal_load(&xp2[(long)c*32 + hl]);
    if (hi==0){ acc2(v[0], s0, s1); acc2(v[1], s2, s3); }
  }
  int j0 = cptr[c], j1 = cptr[c+1];
  int deg = j1 - j0;
  int idx = 0;
  if (lane < deg) idx = csr[j0 + lane];
  int nhc = min((deg+1)>>1, 32);        // UNIFORM for both halves
  int i = 0;
  for (; 2*i+7 < deg && i+4 <= nhc; i+=4){   // uniform condition; edges 2i..2i+7 all valid
    int p0=__shfl(idx, 2*i+hi,   64);
    int p1=__shfl(idx, 2*i+2+hi, 64);
    int p2=__shfl(idx, 2*i+4+hi, 64);
    int p3=__shfl(idx, 2*i+6+hi, 64);
    u32x2 v0=__builtin_nontemporal_load(&xp2[(long)p0*32+hl]);
    u32x2 v1=__builtin_nontemporal_load(&xp2[(long)p1*32+hl]);
    u32x2 v2=__builtin_nontemporal_load(&xp2[(long)p2*32+hl]);
    u32x2 v3=__builtin_nontemporal_load(&xp2[(long)p3*32+hl]);
    acc2(v0[0],s0,s1); acc2(v0[1],s2,s3);
    acc2(v1[0],s0,s1); acc2(v1[1],s2,s3);
    acc2(v2[0],s0,s1); acc2(v2[1],s2,s3);
    acc2(v3[0],s0,s1); acc2(v3[1],s2,s3);
  }
  for (; i<nhc; ++i){                    // uniform trip count; shfl at full EXEC
    int e = 2*i+hi;
    int p = __shfl(idx, e<deg ? e : 0, 64);
    if (e < deg){
      u32x2 v=__builtin_nontemporal_load(&xp2[(long)p*32+hl]);
      acc2(v[0],s0,s1); acc2(v[1],s2,s3);
    }
  }
  if (deg > 64){
    int nt = deg - 64;
    int nth = (nt - hi + 1) >> 1;
    for (int i2=0; i2<nth; ++i2){
      int r = csr[j0 + 64 + 2*i2 + hi];  // scalar load, no shfl -> divergence safe
      u32x2 v = __builtin_nontemporal_load(&xp2[(long)r*32+hl]);
      acc2(v[0],s0,s1); acc2(v[1],s2,s3);
    }
  }
  s0 += __shfl_xor(s0,32,64);
  s1 += __shfl_xor(s1,32,64);
  s2 += __shfl_xor(s2,32,64);
  s3 += __shfl_xor(s3,32,64);
  if (hi==0){
    float m = scOut ? dc*dc : dc;
    u32 lo  = (u32)f2b(m*s0) | ((u32)f2b(m*s1)<<16);
    u32 hi2 = (u32)f2b(m*s2) | ((u32)f2b(m*s3)<<16);
    ((uint2*)outB)[(long)c*32 + hl] = make_uint2(lo, hi2);
  }
}

__device__ __forceinline__ void svec_body(
    const u16* __restrict__ csr, const int* __restrict__ cptr,
    const float* __restrict__ dinv, float* __restrict__ sv, int wid, int lane)
{
  int g = wid / NV, c = wid - g*NV;
  const u16* cg = csr + (long)g*ED;
  const int* cp = cptr + (long)g*(NV+1);
  const float* dv = dinv + (long)g*NV;
  int j0=cp[c], j1=cp[c+1];
  float sum=0.f;
  for (int j=j0+lane;j<j1;j+=64) sum+=dv[cg[j]];
  #pragma unroll
  for (int o=32;o;o>>=1) sum+=__shfl_xor(sum,o,64);
  if (lane==0){ float dc=dv[c]; sv[(long)g*NV+c]=dc*(dc+sum); }
}

// batched over graphs: wid in [0, nGraphs*NV); standard strides NH/ED/(NV+1)/NV
__global__ __launch_bounds__(256) void agg_k(
    const u16* __restrict__ xw, const u16* __restrict__ csr,
    const int* __restrict__ cptr, const float* __restrict__ dinv,
    u16* __restrict__ outB, int scOut)
{
  int wid = blockIdx.x*4 + (threadIdx.x>>6);
  int g = wid / NV, c = wid - g*NV;
  agg_body(xw + (long)g*NH, csr + (long)g*ED, cptr + (long)g*(NV+1),
           dinv + (long)g*NV, outB + (long)g*NH, c, threadIdx.x & 63, scOut);
}

// combo: batched agg (3 graphs) + svec (3 graphs)
__global__ __launch_bounds__(256) void aggsv_k(
    const u16* __restrict__ xw, const u16* __restrict__ csr,
    const int* __restrict__ cptr, const float* __restrict__ dinv,
    u16* __restrict__ outB, int scOut, float* __restrict__ sv)
{
  int lane = threadIdx.x & 63;
  if (blockIdx.x < NG*NV/4){
    int wid = blockIdx.x*4 + (threadIdx.x>>6);
    int g = wid / NV, c = wid - g*NV;
    agg_body(xw + (long)g*NH, csr + (long)g*ED, cptr + (long)g*(NV+1),
             dinv + (long)g*NV, outB + (long)g*NH, c, lane, scOut);
  } else {
    int wid = (blockIdx.x - NG*NV/4)*4 + (threadIdx.x>>6);
    svec_body(csr, cptr, dinv, sv, wid, lane);
  }
}

// --------------- bf16 MFMA GEMM, 128x128 tile, BK=64 (unchanged) -----------------
template<int MODE, int EX>
__global__ __launch_bounds__(256) void gemm_k(
    const void* __restrict__ A_, long sA,
    const u16* __restrict__ Bt, long sB,
    const float* __restrict__ biasCol, long sBias,
    const float* __restrict__ svec, long sS,
    const float* __restrict__ tvec,
    const float* __restrict__ scaleRow, long sSc,
    const float* __restrict__ Add,
    float* __restrict__ Cf, long sCf,
    float* __restrict__ Cf2,
    u16* __restrict__ Cb, long sCb,
    int M, int N, int K, int relu)
{
  __shared__ __align__(16) u16 lsA[128*64];
  __shared__ __align__(16) u16 lsB[128*64];
  const int gz = blockIdx.z;
  const float* Af = (const float*)A_ + (long)gz*sA;
  const u16*   Ab = (const u16*)  A_ + (long)gz*sA;
  const u16* Bp = Bt + (long)gz*sB;
  const int t = threadIdx.x;
  const int lane = t & 63, wv = t >> 6, wm = wv >> 1, wn = wv & 1;
  const int lr = lane & 15, lq = lane >> 4;
  const int ar = t >> 1, ah = t & 1;
  const long grow = (long)blockIdx.x*128 + ar;
  const int colB = blockIdx.y*128 + ar;

  f32x4 acc[4][4];
  #pragma unroll
  for (int m=0;m<4;m++)
    #pragma unroll
    for (int n=0;n<4;n++) acc[m][n] = (f32x4)(0.0f);

  for (int k0=0; k0<K; k0+=64){
    if (k0) __syncthreads();
    u16x8 av[4];
    if (grow < M){
      if (MODE==0){
        const u16x8* s = (const u16x8*)(Ab + grow*(long)K + k0 + ah*32);
        #pragma unroll
        for (int i=0;i<4;i++) av[i] = s[i];
      } else {
        const float4* s = (const float4*)(Af + grow*(long)K + k0 + ah*32);
        #pragma unroll
        for (int i=0;i<4;i++){
          float4 v0 = s[i*2], v1 = s[i*2+1];
          u16x8 w;
          w[0]=f2b(v0.x); w[1]=f2b(v0.y); w[2]=f2b(v0.z); w[3]=f2b(v0.w);
          w[4]=f2b(v1.x); w[5]=f2b(v1.y); w[6]=f2b(v1.z); w[7]=f2b(v1.w);
          av[i] = w;
        }
      }
    } else {
      #pragma unroll
      for (int i=0;i<4;i++) av[i] = (u16x8)((u16)0);
    }
    #pragma unroll
    for (int i=0;i<4;i++){
      int q = ah*4 + i;
      *(u16x8*)&lsA[ar*64 + ((q ^ (ar&7))<<3)] = av[i];
    }
    {
      const u16x8* s = (const u16x8*)(Bp + (long)colB*K + k0 + ah*32);
      #pragma unroll
      for (int i=0;i<4;i++){
        int q = ah*4 + i;
        *(u16x8*)&lsB[ar*64 + ((q ^ (ar&7))<<3)] = s[i];
      }
    }
    __syncthreads();
    #pragma unroll
    for (int kk=0; kk<2; kk++){
      bf16x8 afr[4], bfr[4];
      #pragma unroll
      for (int m=0;m<4;m++){
        int r = wm*64 + m*16 + lr;
        int q = kk*4 + lq;
        afr[m] = __builtin_bit_cast(bf16x8, *(const u16x8*)&lsA[r*64 + ((q ^ (r&7))<<3)]);
      }
      #pragma unroll
      for (int n=0;n<4;n++){
        int r = wn*64 + n*16 + lr;
        int q = kk*4 + lq;
        bfr[n] = __builtin_bit_cast(bf16x8, *(const u16x8*)&lsB[r*64 + ((q ^ (r&7))<<3)]);
      }
      #pragma unroll
      for (int m=0;m<4;m++)
        #pragma unroll
        for (int n=0;n<4;n++)
          acc[m][n] = __builtin_amdgcn_mfma_f32_16x16x32_bf16(afr[m], bfr[n], acc[m][n], 0, 0, 0);
    }
  }
  #pragma unroll
  for (int m=0;m<4;m++){
    long gr0 = (long)blockIdx.x*128 + wm*64 + m*16 + lq*4;
    #pragma unroll
    for (int n=0;n<4;n++){
      int gc = blockIdx.y*128 + wn*64 + n*16 + lr;
      float bb = biasCol[gz*sBias + gc];
      float tv = (svec!=nullptr) ? tvec[gz*sBias + gc] : 0.0f;
      #pragma unroll
      for (int i=0;i<4;i++){
        long gr = gr0 + i;
        if (gr < M){
          float v = acc[m][n][i] + bb;
          if (svec!=nullptr) v += svec[gz*sS + gr]*tv;
          if (relu) v = fmaxf(v, 0.0f);
          if (EX==0){
            if (Cf) Cf[gz*sCf + gr*(long)N + gc] = v;
            if (Cb){
              float sc = scaleRow ? scaleRow[gz*sSc + gr] : 1.0f;
              Cb[gz*sCb + gr*(long)N + gc] = f2b(v*sc);
            }
          } else if (EX==1){
            Cf[gz*sCf + gr*(long)N + gc] = v;
            float z = -(v + Add[gr*(long)N + gc]) * scaleRow[gr];
            Cb[gz*sCb + gr*(long)N + gc] = f2b(z);
          } else {
            Cf[gz*sCf + gr*(long)N + gc] = v;
            float fv = v + Add[gr*(long)N + gc];
            Cf2[gr*(long)N + gc] = fv;
            if (Cb) Cb[gz*sCb + gr*(long)N + gc] = f2b(fv);
          }
        }
      }
    }
  }
}

// --------------- merged: z0 = dinv0.*(-(enc0+enc1)) bf16  AND  h2 = s2(x)t2+b2 ----
__global__ void ewzh2_k(const float4* __restrict__ e0, const float4* __restrict__ e1,
                        const float* __restrict__ dinv0, u16* __restrict__ outB,
                        const float* __restrict__ sv2, const float* __restrict__ t2,
                        const float* __restrict__ b2, float4* __restrict__ outH2){
  int blk = blockIdx.x;
  if (blk < (NH/4)/256){
    int i = blk*256 + threadIdx.x;
    int row = i>>5;
    float d = dinv0[row];
    float4 a = e0[i], b = e1[i];
    float x0=-d*(a.x+b.x), x1=-d*(a.y+b.y), x2=-d*(a.z+b.z), x3=-d*(a.w+b.w);
    ((uint2*)outB)[i] = make_uint2((u32)f2b(x0) | ((u32)f2b(x1)<<16),
                                   (u32)f2b(x2) | ((u32)f2b(x3)<<16));
  } else {
    int i = (blk - (NH/4)/256)*256 + threadIdx.x;
    int row = i>>5, c4 = i&31;
    float s = sv2[row];
    float4 tv = ((const float4*)t2)[c4];
    float4 bb = ((const float4*)b2)[c4];
    outH2[i] = make_float4(s*tv.x+bb.x, s*tv.y+bb.y, s*tv.z+bb.z, s*tv.w+bb.w);
  }
}

// --------------- fc2 + row softmax fused (unchanged) ----------
__global__ __launch_bounds__(256) void fc2sm_k(
    const u16* __restrict__ Ab, const u16* __restrict__ Bw,
    const float* __restrict__ bias, float* __restrict__ Out, int M)
{
  __shared__ __align__(16) u16 lsA[128*64];
  __shared__ __align__(16) u16 lsB[256*64];
  const int t = threadIdx.x;
  const int lane = t & 63, wv = t >> 6, wm = wv >> 1, wn = wv & 1;
  const int lr = lane & 15, lq = lane >> 4;
  const int ar = t >> 1, ah = t & 1;
  const long grow = (long)blockIdx.x*128 + ar;

  f32x4 acc[4][8];
  #pragma unroll
  for (int m=0;m<4;m++)
    #pragma unroll
    for (int n=0;n<8;n++) acc[m][n] = (f32x4)(0.0f);

  for (int k0=0; k0<128; k0+=64){
    if (k0) __syncthreads();
    {
      u16x8 av[4];
      if (grow < M){
        const u16x8* s = (const u16x8*)(Ab + grow*128L + k0 + ah*32);
        #pragma unroll
        for (int i=0;i<4;i++) av[i] = s[i];
      } else {
        #pragma unroll
        for (int i=0;i<4;i++) av[i] = (u16x8)((u16)0);
      }
      #pragma unroll
      for (int i=0;i<4;i++){
        int q = ah*4 + i;
        *(u16x8*)&lsA[ar*64 + ((q ^ (ar&7))<<3)] = av[i];
      }
    }
    #pragma unroll
    for (int rr=0; rr<2; rr++){
      int r = ar + rr*128;
      const u16x8* s = (const u16x8*)(Bw + (long)r*128 + k0 + ah*32);
      #pragma unroll
      for (int i=0;i<4;i++){
        int q = ah*4 + i;
        *(u16x8*)&lsB[r*64 + ((q ^ (r&7))<<3)] = s[i];
      }
    }
    __syncthreads();
    #pragma unroll
    for (int kk=0; kk<2; kk++){
      bf16x8 afr[4], bfr[8];
      #pragma unroll
      for (int m=0;m<4;m++){
        int r = wm*64 + m*16 + lr;
        int q = kk*4 + lq;
        afr[m] = __builtin_bit_cast(bf16x8, *(const u16x8*)&lsA[r*64 + ((q ^ (r&7))<<3)]);
      }
      #pragma unroll
      for (int n=0;n<8;n++){
        int r = wn*128 + n*16 + lr;
        int q = kk*4 + lq;
        bfr[n] = __builtin_bit_cast(bf16x8, *(const u16x8*)&lsB[r*64 + ((q ^ (r&7))<<3)]);
      }
      #pragma unroll
      for (int m=0;m<4;m++)
        #pragma unroll
        for (int n=0;n<8;n++)
          acc[m][n] = __builtin_amdgcn_mfma_f32_16x16x32_bf16(afr[m], bfr[n], acc[m][n], 0, 0, 0);
    }
  }
  #pragma unroll
  for (int n=0;n<8;n++){
    float bb = bias[wn*128 + n*16 + lr];
    #pragma unroll
    for (int m=0;m<4;m++)
      #pragma unroll
      for (int i=0;i<4;i++) acc[m][n][i] += bb;
  }
  __syncthreads();
  float* lsF = (float*)lsA;
  #pragma unroll
  for (int m=0;m<4;m++)
    #pragma unroll
    for (int i=0;i<4;i++){
      float v = acc[m][0][i];
      #pragma unroll
      for (int n=1;n<8;n++) v = fmaxf(v, acc[m][n][i]);
      #pragma unroll
      for (int o=8;o;o>>=1) v = fmaxf(v, __shfl_xor(v, o, 16));
      if (lr==0) lsF[(wm*64 + m*16 + lq*4 + i)*2 + wn] = v;
    }
  __syncthreads();
  #pragma unroll
  for (int m=0;m<4;m++)
    #pragma unroll
    for (int i=0;i<4;i++){
      int rl = wm*64 + m*16 + lq*4 + i;
      float rm = fmaxf(lsF[rl*2], lsF[rl*2+1]);
      float s = 0.f;
      #pragma unroll
      for (int n=0;n<8;n++){
        float e = __expf(acc[m][n][i] - rm);
        acc[m][n][i] = e;
        s += e;
      }
      #pragma unroll
      for (int o=8;o;o>>=1) s += __shfl_xor(s, o, 16);
      if (lr==0) lsF[256 + rl*2 + wn] = s;
    }
  __syncthreads();
  #pragma unroll
  for (int m=0;m<4;m++){
    long gr0 = (long)blockIdx.x*128 + wm*64 + m*16 + lq*4;
    #pragma unroll
    for (int i=0;i<4;i++){
      long gr = gr0 + i;
      if (gr < M){
        int rl = wm*64 + m*16 + lq*4 + i;
        float inv = 1.0f/(lsF[256 + rl*2] + lsF[256 + rl*2 + 1]);
        #pragma unroll
        for (int n=0;n<8;n++){
          int gc = wn*128 + n*16 + lr;
          Out[gr*256L + gc] = acc[m][n][i]*inv;
        }
      }
    }
  }
}

// ===================== host =====================
extern "C" void kernel_launch(void* const* d_in, const int* in_sizes, int n_in,
                              void* d_out, int out_size, void* d_ws, size_t ws_size,
                              hipStream_t stream)
{
  const float* x    = (const float*)d_in[0];
  const int*   ei   = (const int*)  d_in[1];
  const float* fc1W = (const float*)d_in[2];
  const float* fc1b = (const float*)d_in[3];
  const float* c1W  = (const float*)d_in[4];
  const float* c1b  = (const float*)d_in[5];
  const float* c2W  = (const float*)d_in[6];
  const float* c2b  = (const float*)d_in[7];
  const float* d1W  = (const float*)d_in[8];
  const float* d1b  = (const float*)d_in[9];
  const float* d2W  = (const float*)d_in[10];
  const float* d2b  = (const float*)d_in[11];
  const float* fc2W = (const float*)d_in[12];
  const float* fc2b = (const float*)d_in[13];
  (void)in_sizes; (void)n_in; (void)out_size; (void)ws_size;

  float* out  = (float*)d_out;
  float* O_pre = out;
  float* O_enc = out + (long)NG*NH;
  float* O_h   = out + 2L*NG*NH;
  float* O_fin = out + 3L*NG*NH;
  float* O_ls  = O_fin + NH;

  char* p = (char*)d_ws;
  auto alloc = [&](size_t bytes)->void*{
    void* r = (void*)p; p += (bytes + 255) & ~(size_t)255; return r;
  };
  u16* bfA    = (u16*)alloc((size_t)NG*NH*2);
  u16* bfB    = (u16*)alloc((size_t)NG*NH*2);
  u16* bfC    = (u16*)alloc((size_t)NG*NH*2);
  u16* wt_fc1 = (u16*)alloc((size_t)NG*FD*HD*2);
  u16* wt_fc2 = (u16*)alloc((size_t)HD*FD*2);
  u16* wt_ce  = (u16*)alloc((size_t)NG*HD*HD*2);
  u16* wt_cd  = (u16*)alloc((size_t)2*HD*HD*2);
  float* t_enc = (float*)alloc((size_t)NG*HD*4);
  float* t_dec = (float*)alloc((size_t)NG*HD*4);
  u32*  temp  = (u32*) alloc((size_t)NG*ED*4);
  u16*  csr   = (u16*) alloc((size_t)NG*ED*2);
  int*  cptr  = (int*) alloc((size_t)NG*(NV+1)*4);
  int*  btot  = (int*) alloc((size_t)NG*NB*4);
  int*  base  = (int*) alloc((size_t)NG*(NB+1)*4);
  int*  gcur  = (int*) alloc((size_t)NG*NB*4);
  float* dinv = (float*)alloc((size_t)NG*NV*4);
  float* svec = (float*)alloc((size_t)NG*NV*4);

  // ---- binning + CSR + dinv (+ weight prep overlapped) ----
  hipMemsetAsync(btot, 0, (size_t)NG*NB*4, stream);
  htr_k<<<192+833, 256, 0, stream>>>(ei, btot, fc1W, fc2W, c1W, c2W, c1b, d1W, d2W, d1b,
                                     wt_fc1, wt_fc2, wt_ce, wt_cd, t_enc, t_dec);
  scanB_k<<<1, 1024, 0, stream>>>(btot, base, gcur);
  scat_k<<<dim3(CH,NG), 256, 0, stream>>>(ei, gcur, temp);
  sort_k<<<dim3(NB,NG), 256, 0, stream>>>(temp, base, csr, cptr, dinv);

  dim3 g3((NV+127)/128, 1, NG);
  dim3 g1((NV+127)/128, 1, 1);

  // ---- fc1 (batched): pre = xW+b (f32 out) and z = dinv.*pre (bf16) ----
  gemm_k<1,0><<<g3, 256, 0, stream>>>(x, (long)NV*FD, wt_fc1, (long)FD*HD, fc1b, HD,
                                      nullptr, 0, nullptr, dinv, NV, nullptr,
                                      O_pre, NH, nullptr, bfA, NH, NV, HD, FD, 0);

  // ---- encoder hop1 (3 graphs batched, packed with svec) + hop2 (batched) ----
  aggsv_k<<<2*(NG*NV/4), 256, 0, stream>>>(bfA, csr, cptr, dinv, bfB, 1, svec);
  agg_k<<<NG*NV/4, 256, 0, stream>>>(bfB, csr, cptr, dinv, bfC, 0);

  // ---- enc GEMM (batched): enc = relu(bfC @ Wc + s*t + b) ----
  gemm_k<0,0><<<g3, 256, 0, stream>>>(bfC, NH, wt_ce, (long)HD*HD, c2b, HD,
                                      svec, NV, t_enc, nullptr, 0, nullptr,
                                      O_enc, NH, nullptr, nullptr, 0, NV, HD, HD, 1);

  // ---- merged: z0 prep + h2 closed form ----
  ewzh2_k<<<2*(NH/4)/256, 256, 0, stream>>>((const float4*)O_enc, (const float4*)(O_enc+NH), dinv, bfA,
                                            svec + 2L*NV, t_dec + 2*HD, d2b + 2*HD,
                                            (float4*)(O_h + 2L*NH));

  // ---- decoder graph 0 ----
  agg_k<<<NV/4, 256, 0, stream>>>(bfA, csr, cptr, dinv, bfB, 1);
  agg_k<<<NV/4, 256, 0, stream>>>(bfB, csr, cptr, dinv, bfC, 0);
  gemm_k<0,1><<<g1, 256, 0, stream>>>(bfC, 0, wt_cd, 0, d2b, 0,
                                      svec, 0, t_dec, dinv + NV, 0, O_enc + NH,
                                      O_h, 0, nullptr, bfA, 0, NV, HD, HD, 0);

  // ---- decoder graph 1 ----
  agg_k<<<NV/4, 256, 0, stream>>>(bfA, csr + ED, cptr + (NV+1), dinv + NV, bfB, 1);
  agg_k<<<NV/4, 256, 0, stream>>>(bfB, csr + ED, cptr + (NV+1), dinv + NV, bfC, 0);
  gemm_k<0,2><<<g1, 256, 0, stream>>>(bfC, 0, wt_cd + (long)HD*HD, 0, d2b + HD, 0,
                                      svec + NV, 0, t_dec + HD, nullptr, 0, O_h,
                                      O_h + NH, 0, O_fin, bfA, 0, NV, HD, HD, 0);

  // ---- fc2 + softmax (fused) ----
  fc2sm_k<<<(NV+127)/128, 256, 0, stream>>>(bfA, wt_fc2, fc2b, O_ls, NV);
}

// Round 10
// 587.573 us; speedup vs baseline: 1.2021x; 1.2021x over previous
//
#include <hip/hip_runtime.h>
#include <hip/hip_bf16.h>

#define NV 40000
#define FD 256
#define HD 128
#define ED 640000
#define NG 3
#define NH (NV*HD)

#define CH  64            // edge chunks per graph
#define EPC (ED/CH)       // 10000 edges per chunk
#define NB  625           // buckets of 64 nodes

typedef unsigned short u16;
typedef unsigned int   u32;
typedef __attribute__((ext_vector_type(8))) u16    u16x8;
typedef __attribute__((ext_vector_type(8))) __bf16 bf16x8;
typedef __attribute__((ext_vector_type(4))) float  f32x4;

__device__ inline u16 f2b(float f){ __bf16 h = (__bf16)f; return __builtin_bit_cast(u16, h); }
__device__ inline float b2f(u16 u){ u32 x = ((u32)u)<<16; return __builtin_bit_cast(float, x); }
__device__ inline void acc2(u32 w, float&a, float&b){
  a += __builtin_bit_cast(float, w<<16);
  b += __builtin_bit_cast(float, w & 0xFFFF0000u);
}

// ---------------- combo: bucket hist (192 blocks) + weight prep (833 blocks) ----
__device__ inline void tr_seg(const float* __restrict__ src, u16* __restrict__ dst,
                              int K, int NN, long idx, long total){
  if (idx>=total) return;
  long per=(long)K*NN; long mat=idx/per; long rem=idx-mat*per;
  int k=(int)(rem/NN), c=(int)(rem-(long)k*NN);
  dst[mat*per+(long)c*K+k]=f2b(src[idx]);
}

__global__ __launch_bounds__(256) void htr_k(
    const int* __restrict__ ei, int* __restrict__ btot,
    const float* fc1W, const float* fc2W,
    const float* c1W, const float* c2W, const float* c1b,
    const float* d1W, const float* d2W, const float* d1b,
    u16* w_fc1, u16* w_fc2, u16* w_ce, u16* w_cd,
    float* t_enc, float* t_dec)
{
  __shared__ int h[NB];
  int b = blockIdx.x, t = threadIdx.x;
  if (b < 192){
    int ch = b % CH, g = b / CH;
    for (int i=t;i<NB;i+=256) h[i]=0;
    __syncthreads();
    const int* cc = ei + (long)g*2*ED + ED + ch*EPC;
    for (int j=t;j<EPC;j+=256) atomicAdd(&h[cc[j]>>6],1);
    __syncthreads();
    for (int bb=t;bb<NB;bb+=256){ int v=h[bb]; if(v) atomicAdd(&btot[g*NB+bb], v); }
    return;
  }
  int blk = b - 192;
  if (blk < 384){
    tr_seg(fc1W, w_fc1, FD, HD, (long)blk*256+t, (long)NG*FD*HD);
  } else if (blk < 512){
    tr_seg(fc2W, w_fc2, HD, FD, (long)(blk-384)*256+t, (long)HD*FD);
  } else if (blk < 832){
    int bb=blk-512;
    int mat=bb>>6;
    int local=(bb&63)*256+t;
    int n=local>>7, k=local&127;
    const float* W1; const float* W2; u16* dst;
    if (mat<3){ W1=c1W+(long)mat*HD*HD; W2=c2W+(long)mat*HD*HD; dst=w_ce+(long)mat*HD*HD; }
    else { int md=mat-3; W1=d1W+(long)md*HD*HD; W2=d2W+(long)md*HD*HD; dst=w_cd+(long)md*HD*HD; }
    float s=0.f;
    for (int j=0;j<HD;j++) s += W1[k*HD+j]*W2[j*HD+n];
    dst[(long)n*HD+k]=f2b(s);
  } else {
    for (int idx=t; idx<768; idx+=256){
      int which=idx>>7, n=idx&127;
      const float* bv; const float* W; float* dst;
      if (which<3){ bv=c1b+which*HD; W=c2W+(long)which*HD*HD; dst=t_enc+which*HD; }
      else { int w2=which-3; bv=d1b+w2*HD; W=d2W+(long)w2*HD*HD; dst=t_dec+w2*HD; }
      float s=0.f;
      for (int k=0;k<HD;k++) s += bv[k]*W[(long)k*HD+n];
      dst[n]=s;
    }
  }
}

__global__ void scanB_k(const int* __restrict__ btot, int* __restrict__ base, int* __restrict__ gcur){
  __shared__ int wsum[16];
  int tid=threadIdx.x, lane=tid&63, wv=tid>>6;
  for (int g=0; g<NG; ++g){
    int v = (tid<NB)? btot[g*NB+tid] : 0;
    int s=v;
    #pragma unroll
    for (int d=1; d<64; d<<=1){ int u=__shfl_up(s,d,64); if(lane>=d) s+=u; }
    if (lane==63) wsum[wv]=s;
    __syncthreads();
    if (wv==0){
      int t3=(lane<16)?wsum[lane]:0;
      #pragma unroll
      for (int d=1; d<16; d<<=1){ int u=__shfl_up(t3,d,64); if(lane>=d) t3+=u; }
      if (lane<16) wsum[lane]=t3;
    }
    __syncthreads();
    int incl = s + (wv>0? wsum[wv-1]:0);
    if (tid<NB){
      base[g*(NB+1)+tid]=incl-v;
      gcur[g*NB+tid]=incl-v;
      if (tid==NB-1) base[g*(NB+1)+NB]=incl;
    }
    __syncthreads();
  }
}

__global__ __launch_bounds__(256) void scat_k(const int* __restrict__ ei, int* __restrict__ gcur,
                                              u32* __restrict__ temp){
  int ch=blockIdx.x, g=blockIdx.y, t=threadIdx.x;
  __shared__ int h[NB];
  __shared__ int cur[NB];
  for (int i=t;i<NB;i+=256) h[i]=0;
  __syncthreads();
  const int* rr = ei + (long)g*2*ED + ch*EPC;
  const int* cc = rr + ED;
  for (int j=t;j<EPC;j+=256) atomicAdd(&h[cc[j]>>6],1);
  __syncthreads();
  for (int b=t;b<NB;b+=256){ int v=h[b]; cur[b] = v? atomicAdd(&gcur[g*NB+b], v) : 0; }
  __syncthreads();
  u32* tg = temp + (long)g*ED;
  for (int j=t;j<EPC;j+=256){
    int r=rr[j], c=cc[j];
    int pos=atomicAdd(&cur[c>>6],1);
    tg[pos]=((u32)(c&63)<<16)|(u32)r;
  }
}

// bucket-local counting sort -> u16 CSR + cptr + dinv
__global__ __launch_bounds__(256) void sort_k(const u32* __restrict__ temp, const int* __restrict__ base,
                                              u16* __restrict__ csr, int* __restrict__ cptr,
                                              float* __restrict__ dinv){
  int b=blockIdx.x, g=blockIdx.y, t=threadIdx.x;
  __shared__ int cnt[64];
  __shared__ int cur[64];
  if (t<64) cnt[t]=0;
  __syncthreads();
  const u32* tg = temp + (long)g*ED;
  int s=base[g*(NB+1)+b], e=base[g*(NB+1)+b+1];
  for (int i=s+t;i<e;i+=256) atomicAdd(&cnt[tg[i]>>16],1);
  __syncthreads();
  if (t<64){
    int v=cnt[t];
    int sc=v;
    #pragma unroll
    for (int d=1;d<64;d<<=1){ int u=__shfl_up(sc,d,64); if(t>=d) sc+=u; }
    int st = s + sc - v;
    cur[t]=st;
    cptr[(long)g*(NV+1) + b*64 + t] = st;
    if (b==NB-1 && t==63) cptr[(long)g*(NV+1)+NV] = e;
    dinv[(long)g*NV + b*64 + t] = rsqrtf((float)v+1.0f);
  }
  __syncthreads();
  u16* cg = csr + (long)g*ED;
  for (int i=s+t;i<e;i+=256){
    u32 tt=tg[i];
    int pos=atomicAdd(&cur[tt>>16],1);
    cg[pos]=(u16)(tt&0xFFFF);
  }
}

// --------------- agg body: half-wave dwordx2 gather, UNIFORM trip counts --------
// Plain (cached) loads: round-9 A/B test proved the random row-gathers get real
// L2/L3 hits (~10 us/hop benefit) — nontemporal loads regressed 605->706 us.
// EXEC-mask safety (round-8): uniform trip counts for both halves; clamped shfl src.
__device__ __forceinline__ void agg_body(
    const u16* __restrict__ xw, const u16* __restrict__ csr,
    const int* __restrict__ cptr, const float* __restrict__ dinv,
    u16* __restrict__ outB, int c, int lane, int scOut)
{
  const uint2* xp2 = (const uint2*)xw;   // row r: xp2[r*32 + hl] = features 4hl..4hl+3
  int hl = lane & 31;
  int hi = lane >> 5;
  float dc = dinv[c];
  float s0=0.f, s1=0.f, s2=0.f, s3=0.f;
  {
    uint2 v = xp2[(long)c*32 + hl];
    if (hi==0){ acc2(v.x, s0, s1); acc2(v.y, s2, s3); }
  }
  int j0 = cptr[c], j1 = cptr[c+1];
  int deg = j1 - j0;
  int idx = 0;
  if (lane < deg) idx = csr[j0 + lane];
  int nhc = min((deg+1)>>1, 32);        // UNIFORM for both halves
  int i = 0;
  for (; 2*i+7 < deg && i+4 <= nhc; i+=4){   // uniform condition; edges 2i..2i+7 all valid
    int p0=__shfl(idx, 2*i+hi,   64);
    int p1=__shfl(idx, 2*i+2+hi, 64);
    int p2=__shfl(idx, 2*i+4+hi, 64);
    int p3=__shfl(idx, 2*i+6+hi, 64);
    uint2 v0=xp2[(long)p0*32+hl], v1=xp2[(long)p1*32+hl];
    uint2 v2=xp2[(long)p2*32+hl], v3=xp2[(long)p3*32+hl];
    acc2(v0.x,s0,s1); acc2(v0.y,s2,s3);
    acc2(v1.x,s0,s1); acc2(v1.y,s2,s3);
    acc2(v2.x,s0,s1); acc2(v2.y,s2,s3);
    acc2(v3.x,s0,s1); acc2(v3.y,s2,s3);
  }
  for (; i<nhc; ++i){                    // uniform trip count; shfl at full EXEC
    int e = 2*i+hi;
    int p = __shfl(idx, e<deg ? e : 0, 64);
    if (e < deg){
      uint2 v=xp2[(long)p*32+hl];
      acc2(v.x,s0,s1); acc2(v.y,s2,s3);
    }
  }
  if (deg > 64){
    int nt = deg - 64;
    int nth = (nt - hi + 1) >> 1;
    for (int i2=0; i2<nth; ++i2){
      int r = csr[j0 + 64 + 2*i2 + hi];  // scalar load, no shfl -> divergence safe
      uint2 v = xp2[(long)r*32+hl];
      acc2(v.x,s0,s1); acc2(v.y,s2,s3);
    }
  }
  s0 += __shfl_xor(s0,32,64);
  s1 += __shfl_xor(s1,32,64);
  s2 += __shfl_xor(s2,32,64);
  s3 += __shfl_xor(s3,32,64);
  if (hi==0){
    float m = scOut ? dc*dc : dc;
    u32 lo  = (u32)f2b(m*s0) | ((u32)f2b(m*s1)<<16);
    u32 hi2 = (u32)f2b(m*s2) | ((u32)f2b(m*s3)<<16);
    ((uint2*)outB)[(long)c*32 + hl] = make_uint2(lo, hi2);
  }
}

__device__ __forceinline__ void svec_body(
    const u16* __restrict__ csr, const int* __restrict__ cptr,
    const float* __restrict__ dinv, float* __restrict__ sv, int wid, int lane)
{
  int g = wid / NV, c = wid - g*NV;
  const u16* cg = csr + (long)g*ED;
  const int* cp = cptr + (long)g*(NV+1);
  const float* dv = dinv + (long)g*NV;
  int j0=cp[c], j1=cp[c+1];
  float sum=0.f;
  for (int j=j0+lane;j<j1;j+=64) sum+=dv[cg[j]];
  #pragma unroll
  for (int o=32;o;o>>=1) sum+=__shfl_xor(sum,o,64);
  if (lane==0){ float dc=dv[c]; sv[(long)g*NV+c]=dc*(dc+sum); }
}

// batched over graphs: wid in [0, nGraphs*NV); standard strides NH/ED/(NV+1)/NV
__global__ __launch_bounds__(256) void agg_k(
    const u16* __restrict__ xw, const u16* __restrict__ csr,
    const int* __restrict__ cptr, const float* __restrict__ dinv,
    u16* __restrict__ outB, int scOut)
{
  int wid = blockIdx.x*4 + (threadIdx.x>>6);
  int g = wid / NV, c = wid - g*NV;
  agg_body(xw + (long)g*NH, csr + (long)g*ED, cptr + (long)g*(NV+1),
           dinv + (long)g*NV, outB + (long)g*NH, c, threadIdx.x & 63, scOut);
}

// combo: batched agg (3 graphs) + svec (3 graphs)
__global__ __launch_bounds__(256) void aggsv_k(
    const u16* __restrict__ xw, const u16* __restrict__ csr,
    const int* __restrict__ cptr, const float* __restrict__ dinv,
    u16* __restrict__ outB, int scOut, float* __restrict__ sv)
{
  int lane = threadIdx.x & 63;
  if (blockIdx.x < NG*NV/4){
    int wid = blockIdx.x*4 + (threadIdx.x>>6);
    int g = wid / NV, c = wid - g*NV;
    agg_body(xw + (long)g*NH, csr + (long)g*ED, cptr + (long)g*(NV+1),
             dinv + (long)g*NV, outB + (long)g*NH, c, lane, scOut);
  } else {
    int wid = (blockIdx.x - NG*NV/4)*4 + (threadIdx.x>>6);
    svec_body(csr, cptr, dinv, sv, wid, lane);
  }
}

// --------------- bf16 MFMA GEMM, 128x128 tile, BK=64 (unchanged) -----------------
template<int MODE, int EX>
__global__ __launch_bounds__(256) void gemm_k(
    const void* __restrict__ A_, long sA,
    const u16* __restrict__ Bt, long sB,
    const float* __restrict__ biasCol, long sBias,
    const float* __restrict__ svec, long sS,
    const float* __restrict__ tvec,
    const float* __restrict__ scaleRow, long sSc,
    const float* __restrict__ Add,
    float* __restrict__ Cf, long sCf,
    float* __restrict__ Cf2,
    u16* __restrict__ Cb, long sCb,
    int M, int N, int K, int relu)
{
  __shared__ __align__(16) u16 lsA[128*64];
  __shared__ __align__(16) u16 lsB[128*64];
  const int gz = blockIdx.z;
  const float* Af = (const float*)A_ + (long)gz*sA;
  const u16*   Ab = (const u16*)  A_ + (long)gz*sA;
  const u16* Bp = Bt + (long)gz*sB;
  const int t = threadIdx.x;
  const int lane = t & 63, wv = t >> 6, wm = wv >> 1, wn = wv & 1;
  const int lr = lane & 15, lq = lane >> 4;
  const int ar = t >> 1, ah = t & 1;
  const long grow = (long)blockIdx.x*128 + ar;
  const int colB = blockIdx.y*128 + ar;

  f32x4 acc[4][4];
  #pragma unroll
  for (int m=0;m<4;m++)
    #pragma unroll
    for (int n=0;n<4;n++) acc[m][n] = (f32x4)(0.0f);

  for (int k0=0; k0<K; k0+=64){
    if (k0) __syncthreads();
    u16x8 av[4];
    if (grow < M){
      if (MODE==0){
        const u16x8* s = (const u16x8*)(Ab + grow*(long)K + k0 + ah*32);
        #pragma unroll
        for (int i=0;i<4;i++) av[i] = s[i];
      } else {
        const float4* s = (const float4*)(Af + grow*(long)K + k0 + ah*32);
        #pragma unroll
        for (int i=0;i<4;i++){
          float4 v0 = s[i*2], v1 = s[i*2+1];
          u16x8 w;
          w[0]=f2b(v0.x); w[1]=f2b(v0.y); w[2]=f2b(v0.z); w[3]=f2b(v0.w);
          w[4]=f2b(v1.x); w[5]=f2b(v1.y); w[6]=f2b(v1.z); w[7]=f2b(v1.w);
          av[i] = w;
        }
      }
    } else {
      #pragma unroll
      for (int i=0;i<4;i++) av[i] = (u16x8)((u16)0);
    }
    #pragma unroll
    for (int i=0;i<4;i++){
      int q = ah*4 + i;
      *(u16x8*)&lsA[ar*64 + ((q ^ (ar&7))<<3)] = av[i];
    }
    {
      const u16x8* s = (const u16x8*)(Bp + (long)colB*K + k0 + ah*32);
      #pragma unroll
      for (int i=0;i<4;i++){
        int q = ah*4 + i;
        *(u16x8*)&lsB[ar*64 + ((q ^ (ar&7))<<3)] = s[i];
      }
    }
    __syncthreads();
    #pragma unroll
    for (int kk=0; kk<2; kk++){
      bf16x8 afr[4], bfr[4];
      #pragma unroll
      for (int m=0;m<4;m++){
        int r = wm*64 + m*16 + lr;
        int q = kk*4 + lq;
        afr[m] = __builtin_bit_cast(bf16x8, *(const u16x8*)&lsA[r*64 + ((q ^ (r&7))<<3)]);
      }
      #pragma unroll
      for (int n=0;n<4;n++){
        int r = wn*64 + n*16 + lr;
        int q = kk*4 + lq;
        bfr[n] = __builtin_bit_cast(bf16x8, *(const u16x8*)&lsB[r*64 + ((q ^ (r&7))<<3)]);
      }
      #pragma unroll
      for (int m=0;m<4;m++)
        #pragma unroll
        for (int n=0;n<4;n++)
          acc[m][n] = __builtin_amdgcn_mfma_f32_16x16x32_bf16(afr[m], bfr[n], acc[m][n], 0, 0, 0);
    }
  }
  #pragma unroll
  for (int m=0;m<4;m++){
    long gr0 = (long)blockIdx.x*128 + wm*64 + m*16 + lq*4;
    #pragma unroll
    for (int n=0;n<4;n++){
      int gc = blockIdx.y*128 + wn*64 + n*16 + lr;
      float bb = biasCol[gz*sBias + gc];
      float tv = (svec!=nullptr) ? tvec[gz*sBias + gc] : 0.0f;
      #pragma unroll
      for (int i=0;i<4;i++){
        long gr = gr0 + i;
        if (gr < M){
          float v = acc[m][n][i] + bb;
          if (svec!=nullptr) v += svec[gz*sS + gr]*tv;
          if (relu) v = fmaxf(v, 0.0f);
          if (EX==0){
            if (Cf) Cf[gz*sCf + gr*(long)N + gc] = v;
            if (Cb){
              float sc = scaleRow ? scaleRow[gz*sSc + gr] : 1.0f;
              Cb[gz*sCb + gr*(long)N + gc] = f2b(v*sc);
            }
          } else if (EX==1){
            Cf[gz*sCf + gr*(long)N + gc] = v;
            float z = -(v + Add[gr*(long)N + gc]) * scaleRow[gr];
            Cb[gz*sCb + gr*(long)N + gc] = f2b(z);
          } else {
            Cf[gz*sCf + gr*(long)N + gc] = v;
            float fv = v + Add[gr*(long)N + gc];
            Cf2[gr*(long)N + gc] = fv;
            if (Cb) Cb[gz*sCb + gr*(long)N + gc] = f2b(fv);
          }
        }
      }
    }
  }
}

// --------------- merged: z0 = dinv0.*(-(enc0+enc1)) bf16  AND  h2 = s2(x)t2+b2 ----
__global__ void ewzh2_k(const float4* __restrict__ e0, const float4* __restrict__ e1,
                        const float* __restrict__ dinv0, u16* __restrict__ outB,
                        const float* __restrict__ sv2, const float* __restrict__ t2,
                        const float* __restrict__ b2, float4* __restrict__ outH2){
  int blk = blockIdx.x;
  if (blk < (NH/4)/256){
    int i = blk*256 + threadIdx.x;
    int row = i>>5;
    float d = dinv0[row];
    float4 a = e0[i], b = e1[i];
    float x0=-d*(a.x+b.x), x1=-d*(a.y+b.y), x2=-d*(a.z+b.z), x3=-d*(a.w+b.w);
    ((uint2*)outB)[i] = make_uint2((u32)f2b(x0) | ((u32)f2b(x1)<<16),
                                   (u32)f2b(x2) | ((u32)f2b(x3)<<16));
  } else {
    int i = (blk - (NH/4)/256)*256 + threadIdx.x;
    int row = i>>5, c4 = i&31;
    float s = sv2[row];
    float4 tv = ((const float4*)t2)[c4];
    float4 bb = ((const float4*)b2)[c4];
    outH2[i] = make_float4(s*tv.x+bb.x, s*tv.y+bb.y, s*tv.z+bb.z, s*tv.w+bb.w);
  }
}

// --------------- fc2 + row softmax fused (unchanged) ----------
__global__ __launch_bounds__(256) void fc2sm_k(
    const u16* __restrict__ Ab, const u16* __restrict__ Bw,
    const float* __restrict__ bias, float* __restrict__ Out, int M)
{
  __shared__ __align__(16) u16 lsA[128*64];
  __shared__ __align__(16) u16 lsB[256*64];
  const int t = threadIdx.x;
  const int lane = t & 63, wv = t >> 6, wm = wv >> 1, wn = wv & 1;
  const int lr = lane & 15, lq = lane >> 4;
  const int ar = t >> 1, ah = t & 1;
  const long grow = (long)blockIdx.x*128 + ar;

  f32x4 acc[4][8];
  #pragma unroll
  for (int m=0;m<4;m++)
    #pragma unroll
    for (int n=0;n<8;n++) acc[m][n] = (f32x4)(0.0f);

  for (int k0=0; k0<128; k0+=64){
    if (k0) __syncthreads();
    {
      u16x8 av[4];
      if (grow < M){
        const u16x8* s = (const u16x8*)(Ab + grow*128L + k0 + ah*32);
        #pragma unroll
        for (int i=0;i<4;i++) av[i] = s[i];
      } else {
        #pragma unroll
        for (int i=0;i<4;i++) av[i] = (u16x8)((u16)0);
      }
      #pragma unroll
      for (int i=0;i<4;i++){
        int q = ah*4 + i;
        *(u16x8*)&lsA[ar*64 + ((q ^ (ar&7))<<3)] = av[i];
      }
    }
    #pragma unroll
    for (int rr=0; rr<2; rr++){
      int r = ar + rr*128;
      const u16x8* s = (const u16x8*)(Bw + (long)r*128 + k0 + ah*32);
      #pragma unroll
      for (int i=0;i<4;i++){
        int q = ah*4 + i;
        *(u16x8*)&lsB[r*64 + ((q ^ (r&7))<<3)] = s[i];
      }
    }
    __syncthreads();
    #pragma unroll
    for (int kk=0; kk<2; kk++){
      bf16x8 afr[4], bfr[8];
      #pragma unroll
      for (int m=0;m<4;m++){
        int r = wm*64 + m*16 + lr;
        int q = kk*4 + lq;
        afr[m] = __builtin_bit_cast(bf16x8, *(const u16x8*)&lsA[r*64 + ((q ^ (r&7))<<3)]);
      }
      #pragma unroll
      for (int n=0;n<8;n++){
        int r = wn*128 + n*16 + lr;
        int q = kk*4 + lq;
        bfr[n] = __builtin_bit_cast(bf16x8, *(const u16x8*)&lsB[r*64 + ((q ^ (r&7))<<3)]);
      }
      #pragma unroll
      for (int m=0;m<4;m++)
        #pragma unroll
        for (int n=0;n<8;n++)
          acc[m][n] = __builtin_amdgcn_mfma_f32_16x16x32_bf16(afr[m], bfr[n], acc[m][n], 0, 0, 0);
    }
  }
  #pragma unroll
  for (int n=0;n<8;n++){
    float bb = bias[wn*128 + n*16 + lr];
    #pragma unroll
    for (int m=0;m<4;m++)
      #pragma unroll
      for (int i=0;i<4;i++) acc[m][n][i] += bb;
  }
  __syncthreads();
  float* lsF = (float*)lsA;
  #pragma unroll
  for (int m=0;m<4;m++)
    #pragma unroll
    for (int i=0;i<4;i++){
      float v = acc[m][0][i];
      #pragma unroll
      for (int n=1;n<8;n++) v = fmaxf(v, acc[m][n][i]);
      #pragma unroll
      for (int o=8;o;o>>=1) v = fmaxf(v, __shfl_xor(v, o, 16));
      if (lr==0) lsF[(wm*64 + m*16 + lq*4 + i)*2 + wn] = v;
    }
  __syncthreads();
  #pragma unroll
  for (int m=0;m<4;m++)
    #pragma unroll
    for (int i=0;i<4;i++){
      int rl = wm*64 + m*16 + lq*4 + i;
      float rm = fmaxf(lsF[rl*2], lsF[rl*2+1]);
      float s = 0.f;
      #pragma unroll
      for (int n=0;n<8;n++){
        float e = __expf(acc[m][n][i] - rm);
        acc[m][n][i] = e;
        s += e;
      }
      #pragma unroll
      for (int o=8;o;o>>=1) s += __shfl_xor(s, o, 16);
      if (lr==0) lsF[256 + rl*2 + wn] = s;
    }
  __syncthreads();
  #pragma unroll
  for (int m=0;m<4;m++){
    long gr0 = (long)blockIdx.x*128 + wm*64 + m*16 + lq*4;
    #pragma unroll
    for (int i=0;i<4;i++){
      long gr = gr0 + i;
      if (gr < M){
        int rl = wm*64 + m*16 + lq*4 + i;
        float inv = 1.0f/(lsF[256 + rl*2] + lsF[256 + rl*2 + 1]);
        #pragma unroll
        for (int n=0;n<8;n++){
          int gc = wn*128 + n*16 + lr;
          Out[gr*256L + gc] = acc[m][n][i]*inv;
        }
      }
    }
  }
}

// ===================== host =====================
extern "C" void kernel_launch(void* const* d_in, const int* in_sizes, int n_in,
                              void* d_out, int out_size, void* d_ws, size_t ws_size,
                              hipStream_t stream)
{
  const float* x    = (const float*)d_in[0];
  const int*   ei   = (const int*)  d_in[1];
  const float* fc1W = (const float*)d_in[2];
  const float* fc1b = (const float*)d_in[3];
  const float* c1W  = (const float*)d_in[4];
  const float* c1b  = (const float*)d_in[5];
  const float* c2W  = (const float*)d_in[6];
  const float* c2b  = (const float*)d_in[7];
  const float* d1W  = (const float*)d_in[8];
  const float* d1b  = (const float*)d_in[9];
  const float* d2W  = (const float*)d_in[10];
  const float* d2b  = (const float*)d_in[11];
  const float* fc2W = (const float*)d_in[12];
  const float* fc2b = (const float*)d_in[13];
  (void)in_sizes; (void)n_in; (void)out_size; (void)ws_size;

  float* out  = (float*)d_out;
  float* O_pre = out;
  float* O_enc = out + (long)NG*NH;
  float* O_h   = out + 2L*NG*NH;
  float* O_fin = out + 3L*NG*NH;
  float* O_ls  = O_fin + NH;

  char* p = (char*)d_ws;
  auto alloc = [&](size_t bytes)->void*{
    void* r = (void*)p; p += (bytes + 255) & ~(size_t)255; return r;
  };
  u16* bfA    = (u16*)alloc((size_t)NG*NH*2);
  u16* bfB    = (u16*)alloc((size_t)NG*NH*2);
  u16* bfC    = (u16*)alloc((size_t)NG*NH*2);
  u16* wt_fc1 = (u16*)alloc((size_t)NG*FD*HD*2);
  u16* wt_fc2 = (u16*)alloc((size_t)HD*FD*2);
  u16* wt_ce  = (u16*)alloc((size_t)NG*HD*HD*2);
  u16* wt_cd  = (u16*)alloc((size_t)2*HD*HD*2);
  float* t_enc = (float*)alloc((size_t)NG*HD*4);
  float* t_dec = (float*)alloc((size_t)NG*HD*4);
  u32*  temp  = (u32*) alloc((size_t)NG*ED*4);
  u16*  csr   = (u16*) alloc((size_t)NG*ED*2);
  int*  cptr  = (int*) alloc((size_t)NG*(NV+1)*4);
  int*  btot  = (int*) alloc((size_t)NG*NB*4);
  int*  base  = (int*) alloc((size_t)NG*(NB+1)*4);
  int*  gcur  = (int*) alloc((size_t)NG*NB*4);
  float* dinv = (float*)alloc((size_t)NG*NV*4);
  float* svec = (float*)alloc((size_t)NG*NV*4);

  // ---- binning + CSR + dinv (+ weight prep overlapped) ----
  hipMemsetAsync(btot, 0, (size_t)NG*NB*4, stream);
  htr_k<<<192+833, 256, 0, stream>>>(ei, btot, fc1W, fc2W, c1W, c2W, c1b, d1W, d2W, d1b,
                                     wt_fc1, wt_fc2, wt_ce, wt_cd, t_enc, t_dec);
  scanB_k<<<1, 1024, 0, stream>>>(btot, base, gcur);
  scat_k<<<dim3(CH,NG), 256, 0, stream>>>(ei, gcur, temp);
  sort_k<<<dim3(NB,NG), 256, 0, stream>>>(temp, base, csr, cptr, dinv);

  dim3 g3((NV+127)/128, 1, NG);
  dim3 g1((NV+127)/128, 1, 1);

  // ---- fc1 (batched): pre = xW+b (f32 out) and z = dinv.*pre (bf16) ----
  gemm_k<1,0><<<g3, 256, 0, stream>>>(x, (long)NV*FD, wt_fc1, (long)FD*HD, fc1b, HD,
                                      nullptr, 0, nullptr, dinv, NV, nullptr,
                                      O_pre, NH, nullptr, bfA, NH, NV, HD, FD, 0);

  // ---- encoder hop1 (3 graphs batched, packed with svec) + hop2 (batched) ----
  aggsv_k<<<2*(NG*NV/4), 256, 0, stream>>>(bfA, csr, cptr, dinv, bfB, 1, svec);
  agg_k<<<NG*NV/4, 256, 0, stream>>>(bfB, csr, cptr, dinv, bfC, 0);

  // ---- enc GEMM (batched): enc = relu(bfC @ Wc + s*t + b) ----
  gemm_k<0,0><<<g3, 256, 0, stream>>>(bfC, NH, wt_ce, (long)HD*HD, c2b, HD,
                                      svec, NV, t_enc, nullptr, 0, nullptr,
                                      O_enc, NH, nullptr, nullptr, 0, NV, HD, HD, 1);

  // ---- merged: z0 prep + h2 closed form ----
  ewzh2_k<<<2*(NH/4)/256, 256, 0, stream>>>((const float4*)O_enc, (const float4*)(O_enc+NH), dinv, bfA,
                                            svec + 2L*NV, t_dec + 2*HD, d2b + 2*HD,
                                            (float4*)(O_h + 2L*NH));

  // ---- decoder graph 0 ----
  agg_k<<<NV/4, 256, 0, stream>>>(bfA, csr, cptr, dinv, bfB, 1);
  agg_k<<<NV/4, 256, 0, stream>>>(bfB, csr, cptr, dinv, bfC, 0);
  gemm_k<0,1><<<g1, 256, 0, stream>>>(bfC, 0, wt_cd, 0, d2b, 0,
                                      svec, 0, t_dec, dinv + NV, 0, O_enc + NH,
                                      O_h, 0, nullptr, bfA, 0, NV, HD, HD, 0);

  // ---- decoder graph 1 ----
  agg_k<<<NV/4, 256, 0, stream>>>(bfA, csr + ED, cptr + (NV+1), dinv + NV, bfB, 1);
  agg_k<<<NV/4, 256, 0, stream>>>(bfB, csr + ED, cptr + (NV+1), dinv + NV, bfC, 0);
  gemm_k<0,2><<<g1, 256, 0, stream>>>(bfC, 0, wt_cd + (long)HD*HD, 0, d2b + HD, 0,
                                      svec + NV, 0, t_dec + HD, nullptr, 0, O_h,
                                      O_h + NH, 0, O_fin, bfA, 0, NV, HD, HD, 0);

  // ---- fc2 + softmax (fused) ----
  fc2sm_k<<<(NV+127)/128, 256, 0, stream>>>(bfA, wt_fc2, fc2b, O_ls, NV);
}